// Round 1
// baseline (406.482 us; speedup 1.0000x reference)
//
#include <hip/hip_runtime.h>

#define NN 50000
#define NE 800000
#define FIN 128
#define NH 4
#define OPH 32
#define FOUT (NH * OPH)   // 128
#define NSLOPE 0.2f
#define NPB 16            // nodes per block in projection kernel

// ---------------------------------------------------------------------------
// Kernel 1: Wh[h][n][o] = sum_f x[n][f] * W[h][f][o];  e_l/e_r[h][n] = Wh . a
// block = 128 threads (thread t -> h = t>>5, o = t&31), 16 nodes per block.
// x is read at block-uniform addresses -> compiler scalarizes to s_load.
// ---------------------------------------------------------------------------
__global__ __launch_bounds__(128) void k_wh(
    const float* __restrict__ x, const float* __restrict__ W,
    const float* __restrict__ a_l, const float* __restrict__ a_r,
    float* __restrict__ Wh, float* __restrict__ e_l, float* __restrict__ e_r) {
  const int t = threadIdx.x;
  const int h = t >> 5, o = t & 31;
  const int n0 = blockIdx.x * NPB;

  float acc[NPB];
#pragma unroll
  for (int k = 0; k < NPB; ++k) acc[k] = 0.f;

  const float* __restrict__ Wp = W + h * (FIN * OPH) + o;
  const float* __restrict__ xp = x + n0 * FIN;

  for (int f = 0; f < FIN; ++f) {
    const float w = Wp[f * OPH];          // per-thread, L1/L2-cached (W = 64 KB)
#pragma unroll
    for (int k = 0; k < NPB; ++k) {
      acc[k] = fmaf(xp[k * FIN + f], w, acc[k]);   // uniform address -> s_load
    }
  }

  const float al = a_l[h * OPH + o];
  const float ar = a_r[h * OPH + o];
#pragma unroll
  for (int k = 0; k < NPB; ++k) {
    const int n = n0 + k;
    Wh[(h * NN + n) * OPH + o] = acc[k];
    float pl = acc[k] * al;
    float pr = acc[k] * ar;
#pragma unroll
    for (int mm = 16; mm >= 1; mm >>= 1) {   // reduce across the 32 o-lanes
      pl += __shfl_xor(pl, mm);
      pr += __shfl_xor(pr, mm);
    }
    if (o == 0) {
      e_l[h * NN + n] = pl;
      e_r[h * NN + n] = pr;
    }
  }
}

// ---------------------------------------------------------------------------
// CSR build: histogram by dst, exclusive scan, ticket scatter of edge ids.
// ---------------------------------------------------------------------------
__global__ void k_hist(const int* __restrict__ dst, int* __restrict__ counts) {
  const int i = blockIdx.x * blockDim.x + threadIdx.x;
  if (i < NE) atomicAdd(&counts[dst[i]], 1);
}

__global__ __launch_bounds__(512) void k_scan1(const int* __restrict__ counts,
                                               int* __restrict__ offsets,
                                               int* __restrict__ bsums) {
  __shared__ int buf[512];
  const int gid = blockIdx.x * 512 + threadIdx.x;
  const int v = (gid < NN) ? counts[gid] : 0;
  buf[threadIdx.x] = v;
  __syncthreads();
  int incl = v;
  for (int d = 1; d < 512; d <<= 1) {
    const int add = (threadIdx.x >= d) ? buf[threadIdx.x - d] : 0;
    __syncthreads();
    incl += add;
    buf[threadIdx.x] = incl;
    __syncthreads();
  }
  if (gid < NN) offsets[gid] = incl - v;   // exclusive
  if (threadIdx.x == 511) bsums[blockIdx.x] = incl;  // block total
}

__global__ __launch_bounds__(128) void k_scan2(int* __restrict__ bsums, int nb) {
  __shared__ int buf[128];
  const int v = (threadIdx.x < nb) ? bsums[threadIdx.x] : 0;
  buf[threadIdx.x] = v;
  __syncthreads();
  int incl = v;
  for (int d = 1; d < 128; d <<= 1) {
    const int add = (threadIdx.x >= d) ? buf[threadIdx.x - d] : 0;
    __syncthreads();
    incl += add;
    buf[threadIdx.x] = incl;
    __syncthreads();
  }
  if (threadIdx.x < nb) bsums[threadIdx.x] = incl - v;  // exclusive
}

__global__ __launch_bounds__(512) void k_scan3(int* __restrict__ offsets,
                                               const int* __restrict__ bsums) {
  const int gid = blockIdx.x * 512 + threadIdx.x;
  if (gid < NN) offsets[gid] += bsums[blockIdx.x];
  if (gid == NN) offsets[NN] = NE;
}

__global__ void k_scatter(const int* __restrict__ dst,
                          const int* __restrict__ offsets,
                          int* __restrict__ cursor, int* __restrict__ perm) {
  const int i = blockIdx.x * blockDim.x + threadIdx.x;
  if (i < NE) {
    const int d = dst[i];
    const int pos = offsets[d] + atomicAdd(&cursor[d], 1);
    perm[pos] = i;
  }
}

// ---------------------------------------------------------------------------
// Kernel 3: per-dst-node segment softmax + weighted aggregation (gather).
// block = 128 threads = one node; thread t -> (h = t>>5, o = t&31).
// pass 1: segment max (init -1e9 matches reference's maximum(seg_max,-1e9)).
// pass 2: denom += exp(e - m); acc += exp(e - m) * Wh[h][src][o].
// out = acc / (denom + 1e-16)  ==  sum(alpha * Wh[src]).
// ---------------------------------------------------------------------------
__global__ __launch_bounds__(128) void k_agg(
    const int* __restrict__ src, const int* __restrict__ perm,
    const int* __restrict__ offsets,
    const float* __restrict__ e_l, const float* __restrict__ e_r,
    const float* __restrict__ Wh, float* __restrict__ out) {
  const int n = blockIdx.x;
  const int t = threadIdx.x;
  const int h = t >> 5, o = t & 31;

  const int beg = offsets[n];
  const int end = offsets[n + 1];
  const float ern = e_r[h * NN + n];

  float m = -1e9f;
  for (int j = beg; j < end; ++j) {
    const int eid = perm[j];            // uniform -> s_load
    const int s = src[eid];             // uniform -> s_load
    float lg = e_l[h * NN + s] + ern;
    lg = (lg >= 0.f) ? lg : NSLOPE * lg;
    m = fmaxf(m, lg);
  }

  float denom = 0.f;
  float acc = 0.f;
  for (int j = beg; j < end; ++j) {
    const int eid = perm[j];
    const int s = src[eid];
    float lg = e_l[h * NN + s] + ern;
    lg = (lg >= 0.f) ? lg : NSLOPE * lg;
    const float ex = __expf(lg - m);
    denom += ex;
    acc = fmaf(ex, Wh[(h * NN + s) * OPH + o], acc);
  }

  out[n * FOUT + t] = acc / (denom + 1e-16f);
}

// ---------------------------------------------------------------------------
extern "C" void kernel_launch(void* const* d_in, const int* in_sizes, int n_in,
                              void* d_out, int out_size, void* d_ws, size_t ws_size,
                              hipStream_t stream) {
  const float* x   = (const float*)d_in[0];
  const int*   ei  = (const int*)d_in[1];   // [2][E]: src = ei, dst = ei + NE
  const float* W   = (const float*)d_in[2];
  const float* a_l = (const float*)d_in[3];
  const float* a_r = (const float*)d_in[4];
  float* out = (float*)d_out;

  const int* src = ei;
  const int* dst = ei + NE;

  // workspace layout (all 4-byte elements)
  float* Wh      = (float*)d_ws;            // NH*NN*OPH = 6,400,000
  float* e_l     = Wh + NH * NN * OPH;      // NH*NN     =   200,000
  float* e_r     = e_l + NH * NN;           // NH*NN     =   200,000
  int*   counts  = (int*)(e_r + NH * NN);   // NN
  int*   cursor  = counts + NN;             // NN
  int*   offsets = cursor + NN;             // NN+1
  int*   bsums   = offsets + NN + 1;        // 128
  int*   perm    = bsums + 128;             // NE
  (void)ws_size; (void)in_sizes; (void)n_in; (void)out_size;

  hipMemsetAsync(counts, 0, sizeof(int) * 2 * NN, stream);  // counts + cursor

  k_wh<<<NN / NPB, 128, 0, stream>>>(x, W, a_l, a_r, Wh, e_l, e_r);

  k_hist<<<(NE + 255) / 256, 256, 0, stream>>>(dst, counts);

  const int nblk = (NN + 511) / 512;  // 98
  k_scan1<<<nblk, 512, 0, stream>>>(counts, offsets, bsums);
  k_scan2<<<1, 128, 0, stream>>>(bsums, nblk);
  k_scan3<<<nblk, 512, 0, stream>>>(offsets, bsums);

  k_scatter<<<(NE + 255) / 256, 256, 0, stream>>>(dst, offsets, cursor, perm);

  k_agg<<<NN, 128, 0, stream>>>(src, perm, offsets, e_l, e_r, Wh, out);
}

// Round 2
// 236.814 us; speedup vs baseline: 1.7165x; 1.7165x over previous
//
#include <hip/hip_runtime.h>

#define NN 50000
#define NE 800000
#define FIN 128
#define NH 4
#define OPH 32
#define FOUT (NH * OPH)   // 128
#define NSLOPE 0.2f

// ---------------------------------------------------------------------------
// Kernel 1: Wh[n][c] = sum_f x[n][f] * W[h][f][o]  (c = h*32+o, layout [n][128])
//           e_l4[n][h] = Wh[n][h,:] . a_l[h],  e_r4 likewise.
// block = 256 threads, 32 nodes/block. x tile staged in LDS via float4.
// ---------------------------------------------------------------------------
__global__ __launch_bounds__(256) void k_wh(
    const float* __restrict__ x, const float* __restrict__ W,
    const float* __restrict__ a_l, const float* __restrict__ a_r,
    float* __restrict__ Wh, float* __restrict__ e_l4, float* __restrict__ e_r4) {
  __shared__ float xs[32 * 128];   // 16 KB
  const int t = threadIdx.x;
  const int n0 = blockIdx.x * 32;

  // stage x[n0..n0+31][0..127] -> LDS (1024 float4, 4 per thread, coalesced)
#pragma unroll
  for (int i = 0; i < 4; ++i) {
    const int li = t + i * 256;            // float4 index within tile
    const long gf = (long)n0 * FIN + li * 4;
    float4 v;
    if (gf + 3 < (long)NN * FIN) v = *(const float4*)(x + gf);
    else v = make_float4(0.f, 0.f, 0.f, 0.f);
    *(float4*)&xs[li * 4] = v;
  }
  __syncthreads();

  const int c = t & 127;                    // output column
  const int h = c >> 5, o = c & 31;
  const int g = t >> 7;                     // node half: 0 or 1

  float acc[16];
#pragma unroll
  for (int k = 0; k < 16; ++k) acc[k] = 0.f;

  const float* __restrict__ Wp = W + h * (FIN * OPH) + o;

  for (int f0 = 0; f0 < FIN; f0 += 4) {
    const float w0 = Wp[(f0 + 0) * OPH];
    const float w1 = Wp[(f0 + 1) * OPH];
    const float w2 = Wp[(f0 + 2) * OPH];
    const float w3 = Wp[(f0 + 3) * OPH];
#pragma unroll
    for (int k = 0; k < 16; ++k) {
      const float4 xv = *(const float4*)&xs[(g * 16 + k) * FIN + f0];  // broadcast
      acc[k] = fmaf(xv.x, w0, acc[k]);
      acc[k] = fmaf(xv.y, w1, acc[k]);
      acc[k] = fmaf(xv.z, w2, acc[k]);
      acc[k] = fmaf(xv.w, w3, acc[k]);
    }
  }

  const float al = a_l[c];
  const float ar = a_r[c];
#pragma unroll
  for (int k = 0; k < 16; ++k) {
    const int n = n0 + g * 16 + k;
    if (n >= NN) continue;
    Wh[n * FOUT + c] = acc[k];             // coalesced 512B per 128-col group
    float pl = acc[k] * al;
    float pr = acc[k] * ar;
#pragma unroll
    for (int mm = 16; mm >= 1; mm >>= 1) { // reduce across the 32 o-lanes
      pl += __shfl_xor(pl, mm);
      pr += __shfl_xor(pr, mm);
    }
    if (o == 0) {
      e_l4[n * NH + h] = pl;
      e_r4[n * NH + h] = pr;
    }
  }
}

// ---------------------------------------------------------------------------
// CSR build: histogram by dst, exclusive scan, ticket scatter of edge ids.
// ---------------------------------------------------------------------------
__global__ void k_hist(const int* __restrict__ dst, int* __restrict__ counts) {
  const int i = blockIdx.x * blockDim.x + threadIdx.x;
  if (i < NE) atomicAdd(&counts[dst[i]], 1);
}

__global__ __launch_bounds__(512) void k_scan1(const int* __restrict__ counts,
                                               int* __restrict__ offsets,
                                               int* __restrict__ bsums) {
  __shared__ int buf[512];
  const int gid = blockIdx.x * 512 + threadIdx.x;
  const int v = (gid < NN) ? counts[gid] : 0;
  buf[threadIdx.x] = v;
  __syncthreads();
  int incl = v;
  for (int d = 1; d < 512; d <<= 1) {
    const int add = (threadIdx.x >= d) ? buf[threadIdx.x - d] : 0;
    __syncthreads();
    incl += add;
    buf[threadIdx.x] = incl;
    __syncthreads();
  }
  if (gid < NN) offsets[gid] = incl - v;   // exclusive
  if (threadIdx.x == 511) bsums[blockIdx.x] = incl;  // block total
}

__global__ __launch_bounds__(128) void k_scan2(int* __restrict__ bsums, int nb) {
  __shared__ int buf[128];
  const int v = (threadIdx.x < nb) ? bsums[threadIdx.x] : 0;
  buf[threadIdx.x] = v;
  __syncthreads();
  int incl = v;
  for (int d = 1; d < 128; d <<= 1) {
    const int add = (threadIdx.x >= d) ? buf[threadIdx.x - d] : 0;
    __syncthreads();
    incl += add;
    buf[threadIdx.x] = incl;
    __syncthreads();
  }
  if (threadIdx.x < nb) bsums[threadIdx.x] = incl - v;  // exclusive
}

__global__ __launch_bounds__(512) void k_scan3(int* __restrict__ offsets,
                                               const int* __restrict__ bsums) {
  const int gid = blockIdx.x * 512 + threadIdx.x;
  if (gid < NN) offsets[gid] += bsums[blockIdx.x];
  if (gid == NN) offsets[NN] = NE;
}

__global__ void k_scatter(const int* __restrict__ dst,
                          const int* __restrict__ offsets,
                          int* __restrict__ cursor, int* __restrict__ perm) {
  const int i = blockIdx.x * blockDim.x + threadIdx.x;
  if (i < NE) {
    const int d = dst[i];
    const int pos = offsets[d] + atomicAdd(&cursor[d], 1);
    perm[pos] = i;
  }
}

// ---------------------------------------------------------------------------
// Kernel 3: per-dst-node segment softmax + weighted aggregation.
// block = 128 threads = one node.
// Phase M (edge-parallel): per-head segment max, LDS tree reduce.
// Phase A (edge-parallel): ex = exp(lg - m) for all 4 heads; ex,src -> LDS.
// Phase B (col-parallel): thread t = column c; acc += ex[h][j]*Wh[s][c], x4 unroll.
// ---------------------------------------------------------------------------
__global__ __launch_bounds__(128) void k_agg(
    const int* __restrict__ src, const int* __restrict__ perm,
    const int* __restrict__ offsets,
    const float* __restrict__ e_l4, const float* __restrict__ e_r4,
    const float* __restrict__ Wh, float* __restrict__ out) {
  __shared__ float red[4 * 128];
  __shared__ float exs[4][128];
  __shared__ int ss[128];

  const int n = blockIdx.x;
  const int t = threadIdx.x;
  const int h = t >> 5;

  const int beg = offsets[n];
  const int end = offsets[n + 1];
  const float4 ern = *(const float4*)&e_r4[n * NH];

  // ---- phase M: per-head max over edges (edge-parallel, strided) ----
  float m0 = -1e9f, m1 = -1e9f, m2 = -1e9f, m3 = -1e9f;
  for (int j = beg + t; j < end; j += 128) {
    const int eid = perm[j];
    const int s = src[eid];
    const float4 el = *(const float4*)&e_l4[s * NH];
    float l0 = el.x + ern.x; l0 = (l0 >= 0.f) ? l0 : NSLOPE * l0;
    float l1 = el.y + ern.y; l1 = (l1 >= 0.f) ? l1 : NSLOPE * l1;
    float l2 = el.z + ern.z; l2 = (l2 >= 0.f) ? l2 : NSLOPE * l2;
    float l3 = el.w + ern.w; l3 = (l3 >= 0.f) ? l3 : NSLOPE * l3;
    m0 = fmaxf(m0, l0); m1 = fmaxf(m1, l1);
    m2 = fmaxf(m2, l2); m3 = fmaxf(m3, l3);
  }
  red[0 * 128 + t] = m0; red[1 * 128 + t] = m1;
  red[2 * 128 + t] = m2; red[3 * 128 + t] = m3;
  __syncthreads();
  for (int st = 64; st >= 1; st >>= 1) {
    if (t < st) {
#pragma unroll
      for (int hh = 0; hh < 4; ++hh)
        red[hh * 128 + t] = fmaxf(red[hh * 128 + t], red[hh * 128 + t + st]);
    }
    __syncthreads();
  }
  m0 = red[0]; m1 = red[128]; m2 = red[256]; m3 = red[384];
  __syncthreads();

  // ---- chunked phases A (exp -> LDS) + B (weighted gather) ----
  float d0 = 0.f, d1 = 0.f, d2 = 0.f, d3 = 0.f;
  float acc = 0.f;
  for (int c0 = beg; c0 < end; c0 += 128) {
    const int cnt = min(128, end - c0);
    if (t < cnt) {
      const int eid = perm[c0 + t];
      const int s = src[eid];
      ss[t] = s;
      const float4 el = *(const float4*)&e_l4[s * NH];
      float l0 = el.x + ern.x; l0 = (l0 >= 0.f) ? l0 : NSLOPE * l0;
      float l1 = el.y + ern.y; l1 = (l1 >= 0.f) ? l1 : NSLOPE * l1;
      float l2 = el.z + ern.z; l2 = (l2 >= 0.f) ? l2 : NSLOPE * l2;
      float l3 = el.w + ern.w; l3 = (l3 >= 0.f) ? l3 : NSLOPE * l3;
      const float e0 = __expf(l0 - m0);
      const float e1 = __expf(l1 - m1);
      const float e2 = __expf(l2 - m2);
      const float e3 = __expf(l3 - m3);
      exs[0][t] = e0; exs[1][t] = e1; exs[2][t] = e2; exs[3][t] = e3;
      d0 += e0; d1 += e1; d2 += e2; d3 += e3;
    }
    __syncthreads();

    int jl = 0;
    for (; jl + 3 < cnt; jl += 4) {
      const int s0 = ss[jl], s1 = ss[jl + 1], s2 = ss[jl + 2], s3 = ss[jl + 3];
      const float w0 = exs[h][jl],     w1 = exs[h][jl + 1];
      const float w2 = exs[h][jl + 2], w3 = exs[h][jl + 3];
      const float v0 = Wh[s0 * FOUT + t];
      const float v1 = Wh[s1 * FOUT + t];
      const float v2 = Wh[s2 * FOUT + t];
      const float v3 = Wh[s3 * FOUT + t];
      acc = fmaf(w0, v0, acc);
      acc = fmaf(w1, v1, acc);
      acc = fmaf(w2, v2, acc);
      acc = fmaf(w3, v3, acc);
    }
    for (; jl < cnt; ++jl) {
      acc = fmaf(exs[h][jl], Wh[ss[jl] * FOUT + t], acc);
    }
    __syncthreads();
  }

  // ---- denom reduce + write ----
  red[0 * 128 + t] = d0; red[1 * 128 + t] = d1;
  red[2 * 128 + t] = d2; red[3 * 128 + t] = d3;
  __syncthreads();
  for (int st = 64; st >= 1; st >>= 1) {
    if (t < st) {
#pragma unroll
      for (int hh = 0; hh < 4; ++hh)
        red[hh * 128 + t] += red[hh * 128 + t + st];
    }
    __syncthreads();
  }
  const float denom = red[h * 128];
  out[n * FOUT + t] = acc / (denom + 1e-16f);
}

// ---------------------------------------------------------------------------
extern "C" void kernel_launch(void* const* d_in, const int* in_sizes, int n_in,
                              void* d_out, int out_size, void* d_ws, size_t ws_size,
                              hipStream_t stream) {
  const float* x   = (const float*)d_in[0];
  const int*   ei  = (const int*)d_in[1];   // [2][E]: src = ei, dst = ei + NE
  const float* W   = (const float*)d_in[2];
  const float* a_l = (const float*)d_in[3];
  const float* a_r = (const float*)d_in[4];
  float* out = (float*)d_out;

  const int* src = ei;
  const int* dst = ei + NE;

  // workspace layout (all 4-byte elements)
  float* Wh      = (float*)d_ws;            // NN*128 = 6,400,000
  float* e_l4    = Wh + NN * FOUT;          // NN*4
  float* e_r4    = e_l4 + NN * NH;          // NN*4
  int*   counts  = (int*)(e_r4 + NN * NH);  // NN
  int*   cursor  = counts + NN;             // NN
  int*   offsets = cursor + NN;             // NN+1
  int*   bsums   = offsets + NN + 1;        // 128
  int*   perm    = bsums + 128;             // NE
  (void)ws_size; (void)in_sizes; (void)n_in; (void)out_size;

  hipMemsetAsync(counts, 0, sizeof(int) * 2 * NN, stream);  // counts + cursor

  k_wh<<<(NN + 31) / 32, 256, 0, stream>>>(x, W, a_l, a_r, Wh, e_l4, e_r4);

  k_hist<<<(NE + 255) / 256, 256, 0, stream>>>(dst, counts);

  const int nblk = (NN + 511) / 512;  // 98
  k_scan1<<<nblk, 512, 0, stream>>>(counts, offsets, bsums);
  k_scan2<<<1, 128, 0, stream>>>(bsums, nblk);
  k_scan3<<<nblk, 512, 0, stream>>>(offsets, bsums);

  k_scatter<<<(NE + 255) / 256, 256, 0, stream>>>(dst, offsets, cursor, perm);

  k_agg<<<NN, 128, 0, stream>>>(src, perm, offsets, e_l4, e_r4, Wh, out);
}

// Round 3
// 189.686 us; speedup vs baseline: 2.1429x; 1.2485x over previous
//
#include <hip/hip_runtime.h>

#define NN 50000
#define NE 800000
#define FIN 128
#define NH 4
#define OPH 32
#define FOUT (NH * OPH)   // 128
#define NSLOPE 0.2f

// ---------------------------------------------------------------------------
// Kernel 1: Wh[n][c] = sum_f x[n][f] * W[h][f][o]  (c = h*32+o, layout [n][128])
//           e_l4[n][h] = Wh[n][h,:] . a_l[h],  e_r4 likewise.
// block = 256 threads; tile 32 nodes x 128 cols; thread = 4 nodes x 4 cols.
// x tile in LDS (broadcast b128 reads, 2-way = free); W via L1 float4.
// ---------------------------------------------------------------------------
__global__ __launch_bounds__(256) void k_wh(
    const float* __restrict__ x, const float* __restrict__ W,
    const float* __restrict__ a_l, const float* __restrict__ a_r,
    float* __restrict__ Wh, float* __restrict__ e_l4, float* __restrict__ e_r4) {
  __shared__ float xs[32 * 128];   // 16 KB
  const int t = threadIdx.x;
  const int n0 = blockIdx.x * 32;

  // stage x[n0..n0+31][:] -> LDS (1024 float4, 4 per thread, coalesced)
#pragma unroll
  for (int i = 0; i < 4; ++i) {
    const int li = t + i * 256;
    const long gf = (long)n0 * FIN + li * 4;
    float4 v;
    if (gf + 3 < (long)NN * FIN) v = *(const float4*)(x + gf);
    else v = make_float4(0.f, 0.f, 0.f, 0.f);
    *(float4*)&xs[li * 4] = v;
  }
  __syncthreads();

  const int tx = t & 31;            // col group: c0 = tx*4
  const int ty = t >> 5;            // node group: nodes n0 + ty*4 + (0..3)
  const int c0 = tx * 4;
  const int h = tx >> 3;            // head of this col group
  const int o0 = (tx & 7) * 4;

  float acc[4][4];
#pragma unroll
  for (int a = 0; a < 4; ++a)
#pragma unroll
    for (int b = 0; b < 4; ++b) acc[a][b] = 0.f;

  const float* __restrict__ Wp = W + h * (FIN * OPH) + o0;

  for (int f0 = 0; f0 < FIN; f0 += 4) {
    float4 wv[4];
#pragma unroll
    for (int ff = 0; ff < 4; ++ff)
      wv[ff] = *(const float4*)(Wp + (f0 + ff) * OPH);
    float4 xv[4];
#pragma unroll
    for (int nl = 0; nl < 4; ++nl)
      xv[nl] = *(const float4*)&xs[(ty * 4 + nl) * FIN + f0];
#pragma unroll
    for (int nl = 0; nl < 4; ++nl) {
      acc[nl][0] = fmaf(xv[nl].x, wv[0].x, acc[nl][0]);
      acc[nl][1] = fmaf(xv[nl].x, wv[0].y, acc[nl][1]);
      acc[nl][2] = fmaf(xv[nl].x, wv[0].z, acc[nl][2]);
      acc[nl][3] = fmaf(xv[nl].x, wv[0].w, acc[nl][3]);
      acc[nl][0] = fmaf(xv[nl].y, wv[1].x, acc[nl][0]);
      acc[nl][1] = fmaf(xv[nl].y, wv[1].y, acc[nl][1]);
      acc[nl][2] = fmaf(xv[nl].y, wv[1].z, acc[nl][2]);
      acc[nl][3] = fmaf(xv[nl].y, wv[1].w, acc[nl][3]);
      acc[nl][0] = fmaf(xv[nl].z, wv[2].x, acc[nl][0]);
      acc[nl][1] = fmaf(xv[nl].z, wv[2].y, acc[nl][1]);
      acc[nl][2] = fmaf(xv[nl].z, wv[2].z, acc[nl][2]);
      acc[nl][3] = fmaf(xv[nl].z, wv[2].w, acc[nl][3]);
      acc[nl][0] = fmaf(xv[nl].w, wv[3].x, acc[nl][0]);
      acc[nl][1] = fmaf(xv[nl].w, wv[3].y, acc[nl][1]);
      acc[nl][2] = fmaf(xv[nl].w, wv[3].z, acc[nl][2]);
      acc[nl][3] = fmaf(xv[nl].w, wv[3].w, acc[nl][3]);
    }
  }

  const float4 al4 = *(const float4*)&a_l[c0];
  const float4 ar4 = *(const float4*)&a_r[c0];
#pragma unroll
  for (int nl = 0; nl < 4; ++nl) {
    const int n = n0 + ty * 4 + nl;
    if (n >= NN) continue;
    *(float4*)&Wh[n * FOUT + c0] =
        make_float4(acc[nl][0], acc[nl][1], acc[nl][2], acc[nl][3]);
    float pl = acc[nl][0] * al4.x + acc[nl][1] * al4.y +
               acc[nl][2] * al4.z + acc[nl][3] * al4.w;
    float pr = acc[nl][0] * ar4.x + acc[nl][1] * ar4.y +
               acc[nl][2] * ar4.z + acc[nl][3] * ar4.w;
    // sum across the 8 col-groups of this head (lane bits 0..2)
#pragma unroll
    for (int mm = 4; mm >= 1; mm >>= 1) {
      pl += __shfl_xor(pl, mm);
      pr += __shfl_xor(pr, mm);
    }
    if ((tx & 7) == 0) {
      e_l4[n * NH + h] = pl;
      e_r4[n * NH + h] = pr;
    }
  }
}

// ---------------------------------------------------------------------------
// CSR build: histogram by dst, exclusive scan, ticket scatter.
// ---------------------------------------------------------------------------
__global__ void k_hist(const int* __restrict__ dst, int* __restrict__ counts) {
  const int i = blockIdx.x * blockDim.x + threadIdx.x;
  if (i < NE) atomicAdd(&counts[dst[i]], 1);
}

__global__ __launch_bounds__(512) void k_scan1(const int* __restrict__ counts,
                                               int* __restrict__ offsets,
                                               int* __restrict__ bsums) {
  __shared__ int buf[512];
  const int gid = blockIdx.x * 512 + threadIdx.x;
  const int v = (gid < NN) ? counts[gid] : 0;
  buf[threadIdx.x] = v;
  __syncthreads();
  int incl = v;
  for (int d = 1; d < 512; d <<= 1) {
    const int add = (threadIdx.x >= d) ? buf[threadIdx.x - d] : 0;
    __syncthreads();
    incl += add;
    buf[threadIdx.x] = incl;
    __syncthreads();
  }
  if (gid < NN) offsets[gid] = incl - v;
  if (threadIdx.x == 511) bsums[blockIdx.x] = incl;
}

__global__ __launch_bounds__(128) void k_scan2(int* __restrict__ bsums, int nb) {
  __shared__ int buf[128];
  const int v = (threadIdx.x < nb) ? bsums[threadIdx.x] : 0;
  buf[threadIdx.x] = v;
  __syncthreads();
  int incl = v;
  for (int d = 1; d < 128; d <<= 1) {
    const int add = (threadIdx.x >= d) ? buf[threadIdx.x - d] : 0;
    __syncthreads();
    incl += add;
    buf[threadIdx.x] = incl;
    __syncthreads();
  }
  if (threadIdx.x < nb) bsums[threadIdx.x] = incl - v;
}

__global__ __launch_bounds__(512) void k_scan3(int* __restrict__ offsets,
                                               const int* __restrict__ bsums) {
  const int gid = blockIdx.x * 512 + threadIdx.x;
  if (gid < NN) offsets[gid] += bsums[blockIdx.x];
  if (gid == NN) offsets[NN] = NE;
}

// scatter: write src id AND pre-gathered e_l4[src] into segment position.
__global__ void k_scatter(const int* __restrict__ src, const int* __restrict__ dst,
                          const int* __restrict__ offsets, int* __restrict__ cursor,
                          const float* __restrict__ e_l4,
                          int* __restrict__ srcs, float* __restrict__ elp) {
  const int i = blockIdx.x * blockDim.x + threadIdx.x;
  if (i < NE) {
    const int d = dst[i];
    const int s = src[i];
    const int pos = offsets[d] + atomicAdd(&cursor[d], 1);
    srcs[pos] = s;
    *(float4*)&elp[pos * 4] = *(const float4*)&e_l4[s * NH];
  }
}

// ---------------------------------------------------------------------------
// Kernel 3: one WAVE per node, zero barriers. Lane owns cols {lane, lane+64}.
// All reductions are 64-lane shfl butterflies; ss/ex4 LDS is wave-private.
// ---------------------------------------------------------------------------
__global__ __launch_bounds__(256) void k_agg(
    const int* __restrict__ srcs, const float* __restrict__ elp,
    const int* __restrict__ offsets, const float* __restrict__ e_r4,
    const float* __restrict__ Wh, float* __restrict__ out) {
  __shared__ int ssh[4][64];
  __shared__ float4 ex4h[4][64];

  const int w = threadIdx.x >> 6;
  const int lane = threadIdx.x & 63;
  const int n = blockIdx.x * 4 + w;

  const int beg = offsets[n];
  const int end = offsets[n + 1];
  const int deg = end - beg;
  const float4 ern = *(const float4*)&e_r4[n * NH];
  const bool lo = (lane < 32);

  float m0 = -1e9f, m1 = -1e9f, m2 = -1e9f, m3 = -1e9f;
  float D0 = 0.f, D1 = 0.f, D2 = 0.f, D3 = 0.f;
  float acc0 = 0.f, acc1 = 0.f;

  if (deg <= 64) {
    // ---- fast path: logits live in registers, single pass ----
    int s = 0;
    float l0 = -1e9f, l1 = -1e9f, l2 = -1e9f, l3 = -1e9f;
    if (lane < deg) {
      const int j = beg + lane;
      s = srcs[j];
      const float4 el = *(const float4*)&elp[j * 4];
      l0 = el.x + ern.x; l0 = (l0 >= 0.f) ? l0 : NSLOPE * l0;
      l1 = el.y + ern.y; l1 = (l1 >= 0.f) ? l1 : NSLOPE * l1;
      l2 = el.z + ern.z; l2 = (l2 >= 0.f) ? l2 : NSLOPE * l2;
      l3 = el.w + ern.w; l3 = (l3 >= 0.f) ? l3 : NSLOPE * l3;
    }
    m0 = l0; m1 = l1; m2 = l2; m3 = l3;
#pragma unroll
    for (int mm = 32; mm >= 1; mm >>= 1) {
      m0 = fmaxf(m0, __shfl_xor(m0, mm));
      m1 = fmaxf(m1, __shfl_xor(m1, mm));
      m2 = fmaxf(m2, __shfl_xor(m2, mm));
      m3 = fmaxf(m3, __shfl_xor(m3, mm));
    }
    float e0 = 0.f, e1 = 0.f, e2 = 0.f, e3 = 0.f;
    if (lane < deg) {
      e0 = __expf(l0 - m0); e1 = __expf(l1 - m1);
      e2 = __expf(l2 - m2); e3 = __expf(l3 - m3);
      ssh[w][lane] = s;
      ex4h[w][lane] = make_float4(e0, e1, e2, e3);
    }
    D0 = e0; D1 = e1; D2 = e2; D3 = e3;
#pragma unroll 4
    for (int jl = 0; jl < deg; ++jl) {
      const int sj = ssh[w][jl];
      const float4 e4 = ex4h[w][jl];
      const float wA = lo ? e4.x : e4.y;
      const float wB = lo ? e4.z : e4.w;
      const float* __restrict__ row = Wh + (long)sj * FOUT;
      acc0 = fmaf(wA, row[lane], acc0);
      acc1 = fmaf(wB, row[64 + lane], acc1);
    }
  } else {
    // ---- general path: max pass over elp (linear), then chunked ----
    for (int j = beg + lane; j < end; j += 64) {
      const float4 el = *(const float4*)&elp[j * 4];
      float l0 = el.x + ern.x; l0 = (l0 >= 0.f) ? l0 : NSLOPE * l0;
      float l1 = el.y + ern.y; l1 = (l1 >= 0.f) ? l1 : NSLOPE * l1;
      float l2 = el.z + ern.z; l2 = (l2 >= 0.f) ? l2 : NSLOPE * l2;
      float l3 = el.w + ern.w; l3 = (l3 >= 0.f) ? l3 : NSLOPE * l3;
      m0 = fmaxf(m0, l0); m1 = fmaxf(m1, l1);
      m2 = fmaxf(m2, l2); m3 = fmaxf(m3, l3);
    }
#pragma unroll
    for (int mm = 32; mm >= 1; mm >>= 1) {
      m0 = fmaxf(m0, __shfl_xor(m0, mm));
      m1 = fmaxf(m1, __shfl_xor(m1, mm));
      m2 = fmaxf(m2, __shfl_xor(m2, mm));
      m3 = fmaxf(m3, __shfl_xor(m3, mm));
    }
    for (int c0 = beg; c0 < end; c0 += 64) {
      const int cnt = min(64, end - c0);
      if (lane < cnt) {
        const int j = c0 + lane;
        const int s = srcs[j];
        const float4 el = *(const float4*)&elp[j * 4];
        float l0 = el.x + ern.x; l0 = (l0 >= 0.f) ? l0 : NSLOPE * l0;
        float l1 = el.y + ern.y; l1 = (l1 >= 0.f) ? l1 : NSLOPE * l1;
        float l2 = el.z + ern.z; l2 = (l2 >= 0.f) ? l2 : NSLOPE * l2;
        float l3 = el.w + ern.w; l3 = (l3 >= 0.f) ? l3 : NSLOPE * l3;
        const float e0 = __expf(l0 - m0);
        const float e1 = __expf(l1 - m1);
        const float e2 = __expf(l2 - m2);
        const float e3 = __expf(l3 - m3);
        D0 += e0; D1 += e1; D2 += e2; D3 += e3;
        ssh[w][lane] = s;
        ex4h[w][lane] = make_float4(e0, e1, e2, e3);
      }
#pragma unroll 4
      for (int jl = 0; jl < cnt; ++jl) {
        const int sj = ssh[w][jl];
        const float4 e4 = ex4h[w][jl];
        const float wA = lo ? e4.x : e4.y;
        const float wB = lo ? e4.z : e4.w;
        const float* __restrict__ row = Wh + (long)sj * FOUT;
        acc0 = fmaf(wA, row[lane], acc0);
        acc1 = fmaf(wB, row[64 + lane], acc1);
      }
    }
  }

#pragma unroll
  for (int mm = 32; mm >= 1; mm >>= 1) {
    D0 += __shfl_xor(D0, mm);
    D1 += __shfl_xor(D1, mm);
    D2 += __shfl_xor(D2, mm);
    D3 += __shfl_xor(D3, mm);
  }
  const float dA = lo ? D0 : D1;
  const float dB = lo ? D2 : D3;
  out[n * FOUT + lane]      = acc0 / (dA + 1e-16f);
  out[n * FOUT + 64 + lane] = acc1 / (dB + 1e-16f);
}

// ---------------------------------------------------------------------------
extern "C" void kernel_launch(void* const* d_in, const int* in_sizes, int n_in,
                              void* d_out, int out_size, void* d_ws, size_t ws_size,
                              hipStream_t stream) {
  const float* x   = (const float*)d_in[0];
  const int*   ei  = (const int*)d_in[1];   // [2][E]: src = ei, dst = ei + NE
  const float* W   = (const float*)d_in[2];
  const float* a_l = (const float*)d_in[3];
  const float* a_r = (const float*)d_in[4];
  float* out = (float*)d_out;

  const int* src = ei;
  const int* dst = ei + NE;

  // workspace layout (floats; float4-aligned arrays first)
  float* Wh      = (float*)d_ws;            //  6,400,000
  float* e_l4    = Wh + NN * FOUT;          //    200,000
  float* e_r4    = e_l4 + NN * NH;          //    200,000
  float* elp     = e_r4 + NN * NH;          //  3,200,000 (per-edge e_l, permuted)
  int*   counts  = (int*)(elp + (size_t)NE * 4);  // 50,000
  int*   cursor  = counts + NN;             //     50,000
  int*   offsets = cursor + NN;             //     50,001
  int*   bsums   = offsets + NN + 1;        //        128
  int*   srcs    = bsums + 128;             //    800,000
  (void)ws_size; (void)in_sizes; (void)n_in; (void)out_size;

  hipMemsetAsync(counts, 0, sizeof(int) * 2 * NN, stream);  // counts + cursor

  k_wh<<<(NN + 31) / 32, 256, 0, stream>>>(x, W, a_l, a_r, Wh, e_l4, e_r4);

  k_hist<<<(NE + 255) / 256, 256, 0, stream>>>(dst, counts);

  const int nblk = (NN + 511) / 512;  // 98
  k_scan1<<<nblk, 512, 0, stream>>>(counts, offsets, bsums);
  k_scan2<<<1, 128, 0, stream>>>(bsums, nblk);
  k_scan3<<<nblk, 512, 0, stream>>>(offsets, bsums);

  k_scatter<<<(NE + 255) / 256, 256, 0, stream>>>(src, dst, offsets, cursor,
                                                  e_l4, srcs, elp);

  k_agg<<<NN / 4, 256, 0, stream>>>(srcs, elp, offsets, e_r4, Wh, out);
}

// Round 4
// 143.546 us; speedup vs baseline: 2.8317x; 1.3214x over previous
//
#include <hip/hip_runtime.h>

#define NN 50000
#define NE 800000
#define FIN 128
#define NH 4
#define OPH 32
#define FOUT 128
#define NSLOPE 0.2f
#define NWHB ((NN + 31) / 32)      // 1563 wh blocks
#define NHISTB ((NE + 255) / 256)  // 3125 hist blocks

// round-to-nearest-even f32 -> bf16 (finite values)
static __device__ __forceinline__ unsigned int f2bf(float f) {
  unsigned int u = __float_as_uint(f);
  u += 0x7fffu + ((u >> 16) & 1u);
  return u >> 16;
}

// ---------------------------------------------------------------------------
// Kernel 1 (fused): blocks [0, NWHB) compute the projection; blocks
// [NWHB, NWHB+NHISTB) do the dst histogram (independent work, co-scheduled).
// Projection: Whh[n][c] (bf16) = sum_f x[n][f]*W[h][f][o], c = h*32+o;
//             e_l4[n][h], e_r4[n][h] from the fp32 accumulators.
// tile 32 nodes x 128 cols; thread = 4 nodes x 4 cols; x staged in LDS.
// ---------------------------------------------------------------------------
__global__ __launch_bounds__(256) void k_wh_hist(
    const float* __restrict__ x, const float* __restrict__ W,
    const float* __restrict__ a_l, const float* __restrict__ a_r,
    const int* __restrict__ dst, int* __restrict__ counts,
    unsigned int* __restrict__ Whh, float* __restrict__ e_l4,
    float* __restrict__ e_r4) {
  __shared__ float xs[32 * 128];   // 16 KB
  const int t = threadIdx.x;

  if (blockIdx.x >= NWHB) {        // ---- histogram part ----
    const int i = (blockIdx.x - NWHB) * 256 + t;
    if (i < NE) atomicAdd(&counts[dst[i]], 1);
    return;
  }

  const int n0 = blockIdx.x * 32;

  // stage x[n0..n0+31][:] -> LDS (1024 float4, 4 per thread, coalesced)
#pragma unroll
  for (int i = 0; i < 4; ++i) {
    const int li = t + i * 256;
    const long gf = (long)n0 * FIN + li * 4;
    float4 v;
    if (gf + 3 < (long)NN * FIN) v = *(const float4*)(x + gf);
    else v = make_float4(0.f, 0.f, 0.f, 0.f);
    *(float4*)&xs[li * 4] = v;
  }
  __syncthreads();

  const int tx = t & 31;            // col group: c0 = tx*4
  const int ty = t >> 5;            // node group: n0 + ty*4 + (0..3)
  const int c0 = tx * 4;
  const int h = tx >> 3;
  const int o0 = (tx & 7) * 4;

  float acc[4][4];
#pragma unroll
  for (int a = 0; a < 4; ++a)
#pragma unroll
    for (int b = 0; b < 4; ++b) acc[a][b] = 0.f;

  const float* __restrict__ Wp = W + h * (FIN * OPH) + o0;

  for (int f0 = 0; f0 < FIN; f0 += 4) {
    float4 wv[4];
#pragma unroll
    for (int ff = 0; ff < 4; ++ff)
      wv[ff] = *(const float4*)(Wp + (f0 + ff) * OPH);
    float4 xv[4];
#pragma unroll
    for (int nl = 0; nl < 4; ++nl)
      xv[nl] = *(const float4*)&xs[(ty * 4 + nl) * FIN + f0];
#pragma unroll
    for (int nl = 0; nl < 4; ++nl) {
      acc[nl][0] = fmaf(xv[nl].x, wv[0].x, acc[nl][0]);
      acc[nl][1] = fmaf(xv[nl].x, wv[0].y, acc[nl][1]);
      acc[nl][2] = fmaf(xv[nl].x, wv[0].z, acc[nl][2]);
      acc[nl][3] = fmaf(xv[nl].x, wv[0].w, acc[nl][3]);
      acc[nl][0] = fmaf(xv[nl].y, wv[1].x, acc[nl][0]);
      acc[nl][1] = fmaf(xv[nl].y, wv[1].y, acc[nl][1]);
      acc[nl][2] = fmaf(xv[nl].y, wv[1].z, acc[nl][2]);
      acc[nl][3] = fmaf(xv[nl].y, wv[1].w, acc[nl][3]);
      acc[nl][0] = fmaf(xv[nl].z, wv[2].x, acc[nl][0]);
      acc[nl][1] = fmaf(xv[nl].z, wv[2].y, acc[nl][1]);
      acc[nl][2] = fmaf(xv[nl].z, wv[2].z, acc[nl][2]);
      acc[nl][3] = fmaf(xv[nl].z, wv[2].w, acc[nl][3]);
      acc[nl][0] = fmaf(xv[nl].w, wv[3].x, acc[nl][0]);
      acc[nl][1] = fmaf(xv[nl].w, wv[3].y, acc[nl][1]);
      acc[nl][2] = fmaf(xv[nl].w, wv[3].z, acc[nl][2]);
      acc[nl][3] = fmaf(xv[nl].w, wv[3].w, acc[nl][3]);
    }
  }

  const float4 al4 = *(const float4*)&a_l[c0];
  const float4 ar4 = *(const float4*)&a_r[c0];
#pragma unroll
  for (int nl = 0; nl < 4; ++nl) {
    const int n = n0 + ty * 4 + nl;
    if (n >= NN) continue;
    uint2 pk;
    pk.x = f2bf(acc[nl][0]) | (f2bf(acc[nl][1]) << 16);
    pk.y = f2bf(acc[nl][2]) | (f2bf(acc[nl][3]) << 16);
    *(uint2*)&Whh[(size_t)n * 64 + tx * 2] = pk;   // bf16 row, 8B store
    float pl = acc[nl][0] * al4.x + acc[nl][1] * al4.y +
               acc[nl][2] * al4.z + acc[nl][3] * al4.w;
    float pr = acc[nl][0] * ar4.x + acc[nl][1] * ar4.y +
               acc[nl][2] * ar4.z + acc[nl][3] * ar4.w;
#pragma unroll
    for (int mm = 4; mm >= 1; mm >>= 1) {   // sum the 8 col-groups of head h
      pl += __shfl_xor(pl, mm);
      pr += __shfl_xor(pr, mm);
    }
    if ((tx & 7) == 0) {
      e_l4[n * NH + h] = pl;
      e_r4[n * NH + h] = pr;
    }
  }
}

// ---------------------------------------------------------------------------
// Exclusive scan over counts (3 small kernels).
// ---------------------------------------------------------------------------
__global__ __launch_bounds__(512) void k_scan1(const int* __restrict__ counts,
                                               int* __restrict__ offsets,
                                               int* __restrict__ bsums) {
  __shared__ int buf[512];
  const int gid = blockIdx.x * 512 + threadIdx.x;
  const int v = (gid < NN) ? counts[gid] : 0;
  buf[threadIdx.x] = v;
  __syncthreads();
  int incl = v;
  for (int d = 1; d < 512; d <<= 1) {
    const int add = (threadIdx.x >= d) ? buf[threadIdx.x - d] : 0;
    __syncthreads();
    incl += add;
    buf[threadIdx.x] = incl;
    __syncthreads();
  }
  if (gid < NN) offsets[gid] = incl - v;
  if (threadIdx.x == 511) bsums[blockIdx.x] = incl;
}

__global__ __launch_bounds__(128) void k_scan2(int* __restrict__ bsums, int nb) {
  __shared__ int buf[128];
  const int v = (threadIdx.x < nb) ? bsums[threadIdx.x] : 0;
  buf[threadIdx.x] = v;
  __syncthreads();
  int incl = v;
  for (int d = 1; d < 128; d <<= 1) {
    const int add = (threadIdx.x >= d) ? buf[threadIdx.x - d] : 0;
    __syncthreads();
    incl += add;
    buf[threadIdx.x] = incl;
    __syncthreads();
  }
  if (threadIdx.x < nb) bsums[threadIdx.x] = incl - v;
}

__global__ __launch_bounds__(512) void k_scan3(int* __restrict__ offsets,
                                               const int* __restrict__ bsums) {
  const int gid = blockIdx.x * 512 + threadIdx.x;
  if (gid < NN) offsets[gid] += bsums[blockIdx.x];
  if (gid == NN) offsets[NN] = NE;
}

// ticket scatter: only the src id per segment slot.
__global__ void k_scatter(const int* __restrict__ src, const int* __restrict__ dst,
                          const int* __restrict__ offsets, int* __restrict__ cursor,
                          int* __restrict__ srcs) {
  const int i = blockIdx.x * blockDim.x + threadIdx.x;
  if (i < NE) {
    const int d = dst[i];
    const int pos = offsets[d] + atomicAdd(&cursor[d], 1);
    srcs[pos] = src[i];
  }
}

// ---------------------------------------------------------------------------
// Kernel 3: one WAVE per node, zero barriers. Lane owns cols {2*lane, 2*lane+1}
// (same head h = lane>>4 -> one weight, one dword bf16x2 load per edge).
// ---------------------------------------------------------------------------
__global__ __launch_bounds__(256) void k_agg(
    const int* __restrict__ srcs, const int* __restrict__ offsets,
    const float* __restrict__ e_l4, const float* __restrict__ e_r4,
    const unsigned int* __restrict__ Whh, float* __restrict__ out) {
  __shared__ int ssh[4][64];
  __shared__ float exh[4][64][4];

  const int w = threadIdx.x >> 6;
  const int lane = threadIdx.x & 63;
  const int n = blockIdx.x * 4 + w;

  const int beg = offsets[n];
  const int end = offsets[n + 1];
  const int deg = end - beg;
  const float4 ern = *(const float4*)&e_r4[n * NH];
  const int h = lane >> 4;

  float m0 = -1e9f, m1 = -1e9f, m2 = -1e9f, m3 = -1e9f;
  float D0 = 0.f, D1 = 0.f, D2 = 0.f, D3 = 0.f;
  float acc0 = 0.f, acc1 = 0.f;

  if (deg <= 64) {
    // ---- fast path: one pass, logits in registers ----
    int s = 0;
    float l0 = -1e9f, l1 = -1e9f, l2 = -1e9f, l3 = -1e9f;
    if (lane < deg) {
      s = srcs[beg + lane];
      const float4 el = *(const float4*)&e_l4[s * NH];   // L2-resident table
      l0 = el.x + ern.x; l0 = (l0 >= 0.f) ? l0 : NSLOPE * l0;
      l1 = el.y + ern.y; l1 = (l1 >= 0.f) ? l1 : NSLOPE * l1;
      l2 = el.z + ern.z; l2 = (l2 >= 0.f) ? l2 : NSLOPE * l2;
      l3 = el.w + ern.w; l3 = (l3 >= 0.f) ? l3 : NSLOPE * l3;
    }
    m0 = l0; m1 = l1; m2 = l2; m3 = l3;
#pragma unroll
    for (int mm = 32; mm >= 1; mm >>= 1) {
      m0 = fmaxf(m0, __shfl_xor(m0, mm));
      m1 = fmaxf(m1, __shfl_xor(m1, mm));
      m2 = fmaxf(m2, __shfl_xor(m2, mm));
      m3 = fmaxf(m3, __shfl_xor(m3, mm));
    }
    float e0 = 0.f, e1 = 0.f, e2 = 0.f, e3 = 0.f;
    if (lane < deg) {
      e0 = __expf(l0 - m0); e1 = __expf(l1 - m1);
      e2 = __expf(l2 - m2); e3 = __expf(l3 - m3);
      ssh[w][lane] = s;
      *(float4*)exh[w][lane] = make_float4(e0, e1, e2, e3);
    }
    D0 = e0; D1 = e1; D2 = e2; D3 = e3;
#pragma unroll 4
    for (int jl = 0; jl < deg; ++jl) {
      const int sj = ssh[w][jl];
      const float wH = exh[w][jl][h];
      const unsigned int v = Whh[(size_t)sj * 64 + lane];
      acc0 = fmaf(wH, __uint_as_float(v << 16), acc0);
      acc1 = fmaf(wH, __uint_as_float(v & 0xffff0000u), acc1);
    }
  } else {
    // ---- general path (deg>64 is rare at E/N=16): max pass, then chunks ----
    for (int j = beg + lane; j < end; j += 64) {
      const int s = srcs[j];
      const float4 el = *(const float4*)&e_l4[s * NH];
      float l0 = el.x + ern.x; l0 = (l0 >= 0.f) ? l0 : NSLOPE * l0;
      float l1 = el.y + ern.y; l1 = (l1 >= 0.f) ? l1 : NSLOPE * l1;
      float l2 = el.z + ern.z; l2 = (l2 >= 0.f) ? l2 : NSLOPE * l2;
      float l3 = el.w + ern.w; l3 = (l3 >= 0.f) ? l3 : NSLOPE * l3;
      m0 = fmaxf(m0, l0); m1 = fmaxf(m1, l1);
      m2 = fmaxf(m2, l2); m3 = fmaxf(m3, l3);
    }
#pragma unroll
    for (int mm = 32; mm >= 1; mm >>= 1) {
      m0 = fmaxf(m0, __shfl_xor(m0, mm));
      m1 = fmaxf(m1, __shfl_xor(m1, mm));
      m2 = fmaxf(m2, __shfl_xor(m2, mm));
      m3 = fmaxf(m3, __shfl_xor(m3, mm));
    }
    for (int c0 = beg; c0 < end; c0 += 64) {
      const int cnt = min(64, end - c0);
      if (lane < cnt) {
        const int j = c0 + lane;
        const int s = srcs[j];
        const float4 el = *(const float4*)&e_l4[s * NH];
        float l0 = el.x + ern.x; l0 = (l0 >= 0.f) ? l0 : NSLOPE * l0;
        float l1 = el.y + ern.y; l1 = (l1 >= 0.f) ? l1 : NSLOPE * l1;
        float l2 = el.z + ern.z; l2 = (l2 >= 0.f) ? l2 : NSLOPE * l2;
        float l3 = el.w + ern.w; l3 = (l3 >= 0.f) ? l3 : NSLOPE * l3;
        const float e0 = __expf(l0 - m0);
        const float e1 = __expf(l1 - m1);
        const float e2 = __expf(l2 - m2);
        const float e3 = __expf(l3 - m3);
        D0 += e0; D1 += e1; D2 += e2; D3 += e3;
        ssh[w][lane] = s;
        *(float4*)exh[w][lane] = make_float4(e0, e1, e2, e3);
      }
#pragma unroll 4
      for (int jl = 0; jl < cnt; ++jl) {
        const int sj = ssh[w][jl];
        const float wH = exh[w][jl][h];
        const unsigned int v = Whh[(size_t)sj * 64 + lane];
        acc0 = fmaf(wH, __uint_as_float(v << 16), acc0);
        acc1 = fmaf(wH, __uint_as_float(v & 0xffff0000u), acc1);
      }
    }
  }

#pragma unroll
  for (int mm = 32; mm >= 1; mm >>= 1) {
    D0 += __shfl_xor(D0, mm);
    D1 += __shfl_xor(D1, mm);
    D2 += __shfl_xor(D2, mm);
    D3 += __shfl_xor(D3, mm);
  }
  const float dH = (h == 0) ? D0 : (h == 1) ? D1 : (h == 2) ? D2 : D3;
  const float inv = 1.f / (dH + 1e-16f);
  *(float2*)&out[(size_t)n * FOUT + 2 * lane] =
      make_float2(acc0 * inv, acc1 * inv);
}

// ---------------------------------------------------------------------------
extern "C" void kernel_launch(void* const* d_in, const int* in_sizes, int n_in,
                              void* d_out, int out_size, void* d_ws, size_t ws_size,
                              hipStream_t stream) {
  const float* x   = (const float*)d_in[0];
  const int*   ei  = (const int*)d_in[1];   // [2][E]: src = ei, dst = ei + NE
  const float* W   = (const float*)d_in[2];
  const float* a_l = (const float*)d_in[3];
  const float* a_r = (const float*)d_in[4];
  float* out = (float*)d_out;

  const int* src = ei;
  const int* dst = ei + NE;

  // workspace layout (4-byte elements, 16B-aligned arrays first)
  unsigned int* Whh = (unsigned int*)d_ws;        // NN*64 uints (bf16x2) = 12.8MB
  float* e_l4    = (float*)(Whh + (size_t)NN * 64);  // NN*4
  float* e_r4    = e_l4 + NN * NH;                   // NN*4
  int*   counts  = (int*)(e_r4 + NN * NH);           // NN
  int*   cursor  = counts + NN;                      // NN
  int*   offsets = cursor + NN;                      // NN+1
  int*   bsums   = offsets + NN + 1;                 // 128
  int*   srcs    = bsums + 128;                      // NE
  (void)ws_size; (void)in_sizes; (void)n_in; (void)out_size;

  hipMemsetAsync(counts, 0, sizeof(int) * 2 * NN, stream);  // counts + cursor

  k_wh_hist<<<NWHB + NHISTB, 256, 0, stream>>>(x, W, a_l, a_r, dst, counts,
                                               Whh, e_l4, e_r4);

  const int nblk = (NN + 511) / 512;  // 98
  k_scan1<<<nblk, 512, 0, stream>>>(counts, offsets, bsums);
  k_scan2<<<1, 128, 0, stream>>>(bsums, nblk);
  k_scan3<<<nblk, 512, 0, stream>>>(offsets, bsums);

  k_scatter<<<(NE + 255) / 256, 256, 0, stream>>>(src, dst, offsets, cursor, srcs);

  k_agg<<<NN / 4, 256, 0, stream>>>(srcs, offsets, e_l4, e_r4, Whh, out);
}